// Round 15
// baseline (552.171 us; speedup 1.0000x reference)
//
#include <hip/hip_runtime.h>
#include <hip/hip_bf16.h>
#include <cstdint>
#include <cstddef>

// Problem constants
#define Hh    12
#define Nseq  2048
#define PSTR  1152      // concat projection width: 192 q | 384 kv | 144 qp | 432 kvp
#define EPSm  1e-8f
#define MASKV 1024.0f   // (mi*M)*mj + (-M)*1 == 0 exactly when masks==1
#define NBLK  768u

typedef unsigned short ushort_t;
typedef __attribute__((ext_vector_type(8))) short bf8_t;   // 8 bf16 (4 VGPRs)
typedef __attribute__((ext_vector_type(4))) short s4_t;    // 4 bf16 (2 VGPRs)
typedef __attribute__((ext_vector_type(4))) float f4_t;    // MFMA C/D

// ws offsets (floats). Total 5,051,536 fl = 20.2 MB <= proven 29.1 MB budget.
#define OFF_PALL   0         // fp32 [2048][1152]
#define OFF_WALLB  2359296   // bf16 [1152][384]
#define OFF_BALL   2580480   // fp32 [1152]
#define OFF_SB     2581632   // bf16 [2048][384]
#define OFF_WOUTB  2974848   // bf16 [384][576]
#define OFF_FEATSB 3085440   // bf16 [2048][576]
#define OFF_AU     3675264   // bf16 [12][2048][32]
#define OFF_KU     4068480   // bf16 [12][2048][32]
#define OFF_VU     4461696   // bf16 [12][64][48][32] tile-blocked (r11-verified)
#define OFF_BAR    5051520   // 4 x uint barrier counters (memset to 0 pre-launch)
#define WS_FLOATS  5051536

__device__ __forceinline__ ushort_t bfr(float x) {   // fp32 -> bf16 bits, RNE
    union { float f; uint32_t u; } v; v.f = x;
    uint32_t r = v.u + 0x7FFFu + ((v.u >> 16) & 1u);
    return (ushort_t)(r >> 16);
}

// Grid barrier: capacity-guaranteed co-residency (768 blocks = 3/CU x 256 CU,
// LDS 37KB x 3 = 111KB < 160KB, __launch_bounds__(256,3)). Device-scope
// atomics + fences per G16. Distinct counter per barrier (no reuse).
__device__ __forceinline__ void gridbar(unsigned* c) {
    __syncthreads();
    if (threadIdx.x == 0) {
        __threadfence();   // release: drain + L2 writeback
        __hip_atomic_fetch_add(c, 1u, __ATOMIC_ACQ_REL, __HIP_MEMORY_SCOPE_AGENT);
        while (__hip_atomic_load(c, __ATOMIC_ACQUIRE, __HIP_MEMORY_SCOPE_AGENT) < NBLK)
            __builtin_amdgcn_s_sleep(2);
        __threadfence();   // acquire: invalidate local caches
    }
    __syncthreads();
}

__device__ __forceinline__ bf8_t expack(f4_t s) {   // exp -> bf16 low4, zero high
    s4_t p;
    p[0] = (short)bfr(__expf(s[0]));
    p[1] = (short)bfr(__expf(s[1]));
    p[2] = (short)bfr(__expf(s[2]));
    p[3] = (short)bfr(__expf(s[3]));
    s4_t z = (s4_t)0;
    return __builtin_shufflevector(p, z, 0, 1, 2, 3, 4, 5, 6, 7);
}

__device__ __forceinline__ bf8_t vpad(s4_t v) {     // V low4, zero high
    s4_t z = (s4_t)0;
    return __builtin_shufflevector(v, z, 0, 1, 2, 3, 4, 5, 6, 7);
}

struct KVTile { bf8_t kb0, kb1; s4_t v[6]; };

__device__ __forceinline__ KVTile load_tile(
    const ushort_t* __restrict__ kb_base, const ushort_t* __restrict__ vt,
    int m, int quad)
{
    KVTile tl;
    tl.kb0  = *(const bf8_t*)(kb_base);
    tl.kb1  = *(const bf8_t*)(kb_base + 16 * 32);
    tl.v[0] = *(const s4_t*)(vt +        m * 32 +      quad * 4);
    tl.v[1] = *(const s4_t*)(vt +  512 + m * 32 +      quad * 4);
    tl.v[2] = *(const s4_t*)(vt + 1024 + m * 32 +      quad * 4);
    tl.v[3] = *(const s4_t*)(vt +        m * 32 + 16 + quad * 4);
    tl.v[4] = *(const s4_t*)(vt +  512 + m * 32 + 16 + quad * 4);
    tl.v[5] = *(const s4_t*)(vt + 1024 + m * 32 + 16 + quad * 4);
    return tl;
}

// Shared-memory union across phases (max member 36992 B -> 3 blocks/CU safe)
union ShU {
    struct { ushort_t As[64][40]; ushort_t Bs[64][40]; } g;  // 10240 B (gemm)
    float S[8][1156];                                        // 36992 B (pack)
    float red[4][32][49];                                    // 25088 B (attn)
};

// bf16 64x64 MFMA GEMM tile (r8/r12-verified math), as device function.
__device__ __forceinline__ void gemm64(
    int bx, int by, int t,
    const ushort_t* __restrict__ A, const ushort_t* __restrict__ W,
    const float* __restrict__ bias, float* __restrict__ C,
    int Nn, int K, ShU& sh)
{
    const int bm = by * 64, bn = bx * 64;
    const int w = t >> 6, lane = t & 63;
    const int m = lane & 15, quad = lane >> 4;
    const int wm = (w >> 1) * 32, wn = (w & 1) * 32;

    f4_t acc[2][2];
    #pragma unroll
    for (int i2 = 0; i2 < 2; ++i2)
        #pragma unroll
        for (int j2 = 0; j2 < 2; ++j2)
            acc[i2][j2] = (f4_t){0.f, 0.f, 0.f, 0.f};

    for (int k0 = 0; k0 < K; k0 += 32) {
        {
            int r = t >> 2, kk = (t & 3) * 8;
            *(uint4*)&sh.g.As[r][kk] = *(const uint4*)&A[(size_t)(bm + r) * K + k0 + kk];
            *(uint4*)&sh.g.Bs[r][kk] = *(const uint4*)&W[(size_t)(bn + r) * K + k0 + kk];
        }
        __syncthreads();
        bf8_t af[2], bfv[2];
        #pragma unroll
        for (int x = 0; x < 2; ++x) {
            af[x]  = *(const bf8_t*)&sh.g.As[wm + x * 16 + m][quad * 8];
            bfv[x] = *(const bf8_t*)&sh.g.Bs[wn + x * 16 + m][quad * 8];
        }
        #pragma unroll
        for (int i2 = 0; i2 < 2; ++i2)
            #pragma unroll
            for (int j2 = 0; j2 < 2; ++j2)
                acc[i2][j2] = __builtin_amdgcn_mfma_f32_16x16x32_bf16(
                    af[i2], bfv[j2], acc[i2][j2], 0, 0, 0);
        __syncthreads();
    }

    #pragma unroll
    for (int j2 = 0; j2 < 2; ++j2) {
        int col = bn + wn + j2 * 16 + m;
        float bb = bias[col];
        #pragma unroll
        for (int i2 = 0; i2 < 2; ++i2)
            #pragma unroll
            for (int r = 0; r < 4; ++r) {
                int row = bm + wm + i2 * 16 + quad * 4 + r;
                C[(size_t)row * Nn + col] = acc[i2][j2][r] + bb;
            }
    }
}

// ---------------------------------------------------------------------------
// MEGAKERNEL: prep | gemm1 | pack | attn+fin | gemm2, one launch, 4 barriers.
// ---------------------------------------------------------------------------
__global__ __launch_bounds__(256, 3) void mega(
    const float* __restrict__ s, const float* __restrict__ rot,
    const float* __restrict__ trans, const float* __restrict__ mask,
    const float* __restrict__ Wq, const float* __restrict__ bq,
    const float* __restrict__ Wkv, const float* __restrict__ bkv,
    const float* __restrict__ Wqp, const float* __restrict__ bqp,
    const float* __restrict__ Wkvp, const float* __restrict__ bkvp,
    const float* __restrict__ hwv, const float* __restrict__ Wout,
    const float* __restrict__ bout,
    float* __restrict__ Pall, ushort_t* __restrict__ Wallb,
    float* __restrict__ ball, ushort_t* __restrict__ sb,
    ushort_t* __restrict__ Woutb, ushort_t* __restrict__ featsb,
    ushort_t* __restrict__ AU, ushort_t* __restrict__ KU,
    ushort_t* __restrict__ VU, unsigned* __restrict__ bar,
    float* __restrict__ out)
{
    __shared__ ShU sh;
    const int bid = blockIdx.x;
    const int t   = threadIdx.x;
    const int base = bid * 256 + t;

    // ===== phase 0: prep (r7/r8-verified conversions, grid-stride) =====
    for (int idx = base; idx < 2048 * 384; idx += 768 * 256)
        sb[idx] = bfr(s[idx]);
    for (int idx = base; idx < 1152 * 384; idx += 768 * 256) {
        int r = idx / 384, c = idx % 384;
        float v;
        if (r < 192)      v = Wq [(size_t)r * 384 + c];
        else if (r < 576) v = Wkv[(size_t)(r - 192) * 384 + c];
        else if (r < 720) v = Wqp[(size_t)(r - 576) * 384 + c];
        else              v = Wkvp[(size_t)(r - 720) * 384 + c];
        Wallb[idx] = bfr(v);
    }
    for (int idx = base; idx < 384 * 576; idx += 768 * 256)
        Woutb[idx] = bfr(Wout[idx]);
    if (base < 1152) {
        float v;
        if (base < 192)      v = bq[base];
        else if (base < 576) v = bkv[base - 192];
        else if (base < 720) v = bqp[base - 576];
        else                 v = bkvp[base - 720];
        ball[base] = v;
    }
    gridbar(bar + 0);

    // ===== phase 1: gemm1 Pall = sb @ Wallb^T + ball  (576 tiles) =====
    if (bid < 576)
        gemm64(bid % 18, bid / 18, t, sb, Wallb, ball, Pall, PSTR, 384, sh);
    gridbar(bar + 1);

    // ===== phase 2: pack_aug (r11-verified; 256 active blocks) =====
    if (bid < 256) {
        const int n0 = bid * 8;
        #pragma unroll
        for (int u = 0; u < 9; ++u) {
            int f = t + u * 256;                 // 0..2303
            int rr = f / 288, c4 = f % 288;
            float4 v = *(const float4*)&Pall[(size_t)(n0 + rr) * PSTR + c4 * 4];
            *(float4*)&sh.S[rr][c4 * 4] = v;
        }
        __syncthreads();

        if (t < 96) {
            const int nl = t & 7, h = t >> 3;
            const int n  = n0 + nl;
            const float* row = sh.S[nl];

            const float whw = 0.5f * logf(1.0f + expf(hwv[h])) * 0.13608276348795434f;
            const float scale_a = 0.14433756729740643f;   // sqrt(1/48)

            float R[9], T[3];
            #pragma unroll
            for (int z = 0; z < 9; ++z) R[z] = rot[(size_t)n * 9 + z];
            #pragma unroll
            for (int d = 0; d < 3; ++d) T[d] = trans[(size_t)n * 3 + d];

            float qpv[12], q2 = 0.f;
            #pragma unroll
            for (int p = 0; p < 4; ++p) {
                float r0 = row[576 +   0 + h * 4 + p];
                float r1 = row[576 +  48 + h * 4 + p];
                float r2 = row[576 +  96 + h * 4 + p];
                #pragma unroll
                for (int d = 0; d < 3; ++d) {
                    float o = R[d*3+0]*r0 + R[d*3+1]*r1 + R[d*3+2]*r2 + T[d];
                    qpv[p * 3 + d] = o;
                    q2 += o * o;
                }
            }

            float kpv[12], vpv[24], k2 = 0.f;
            #pragma unroll
            for (int pt = 0; pt < 12; ++pt) {
                float r0 = row[720 +   0 + h * 12 + pt];
                float r1 = row[720 + 144 + h * 12 + pt];
                float r2 = row[720 + 288 + h * 12 + pt];
                #pragma unroll
                for (int d = 0; d < 3; ++d) {
                    float o = R[d*3+0]*r0 + R[d*3+1]*r1 + R[d*3+2]*r2 + T[d];
                    if (pt < 4) { kpv[pt * 3 + d] = o; k2 += o * o; }
                    else        { vpv[(pt - 4) * 3 + d] = o; }
                }
            }

            const float mi = mask[n];

            __align__(16) ushort_t a32[32];
            #pragma unroll
            for (int c = 0; c < 16; ++c) a32[c] = bfr(row[h * 16 + c] * scale_a);
            #pragma unroll
            for (int z = 0; z < 12; ++z) a32[16 + z] = bfr(qpv[z] * (2.0f * whw));
            a32[28] = bfr(-whw);
            a32[29] = bfr(-whw * q2);
            a32[30] = bfr(mi * MASKV);
            a32[31] = bfr(-MASKV);
            ushort_t* adst = AU + ((size_t)h * Nseq + n) * 32;
            #pragma unroll
            for (int u = 0; u < 4; ++u) ((uint4*)adst)[u] = ((const uint4*)a32)[u];

            const float* kvrow = row + 192 + h * 32;
            __align__(16) ushort_t k32[32];
            #pragma unroll
            for (int c = 0; c < 16; ++c) k32[c] = bfr(kvrow[c]);
            #pragma unroll
            for (int z = 0; z < 12; ++z) k32[16 + z] = bfr(kpv[z]);
            k32[28] = bfr(k2);
            k32[29] = 0x3F80;
            k32[30] = bfr(mi);
            k32[31] = 0x3F80;
            ushort_t* kdst = KU + ((size_t)h * Nseq + n) * 32;
            #pragma unroll
            for (int u = 0; u < 4; ++u) ((uint4*)kdst)[u] = ((const uint4*)k32)[u];

            ushort_t* vb = VU + (size_t)h * 98304 + (size_t)(n >> 5) * 1536 + (n & 31);
            #pragma unroll
            for (int c = 0; c < 16; ++c) vb[c * 32] = bfr(kvrow[16 + c]);
            #pragma unroll
            for (int z = 0; z < 24; ++z) vb[(16 + z) * 32] = bfr(vpv[z]);
            vb[40 * 32] = 0x3F80;
            #pragma unroll
            for (int c = 41; c < 48; ++c) vb[c * 32] = 0;
        }
    }
    gridbar(bar + 2);

    // ===== phase 3: attention + fused epilogue (r11/r12-verified, 768) =====
    {
        const int h    = bid >> 6;
        const int ib   = bid & 63;
        const int w    = t >> 6;
        const int lane = t & 63;
        const int m    = lane & 15;
        const int quad = lane >> 4;
        const int i0   = ib * 32;

        bf8_t afA = *(const bf8_t*)(AU + ((size_t)h * Nseq + i0 +      m) * 32 + quad * 8);
        bf8_t afB = *(const bf8_t*)(AU + ((size_t)h * Nseq + i0 + 16 + m) * 32 + quad * 8);

        f4_t acc[6];
        #pragma unroll
        for (int z = 0; z < 6; ++z) acc[z] = (f4_t){0.f, 0.f, 0.f, 0.f};

        const int jb0 = w * 512;
        const ushort_t* kb_base = KU + ((size_t)h * Nseq + jb0 + m) * 32 + quad * 8;
        const ushort_t* v_base  = VU + (size_t)h * 98304 + (size_t)jb0 * 48;

        KVTile cur = load_tile(kb_base, v_base, m, quad);

        #pragma unroll
        for (int jt = 0; jt < 16; ++jt) {
            f4_t zz = (f4_t){0.f, 0.f, 0.f, 0.f};
            f4_t sXA = __builtin_amdgcn_mfma_f32_16x16x32_bf16(cur.kb0, afA, zz, 0, 0, 0);
            f4_t sXB = __builtin_amdgcn_mfma_f32_16x16x32_bf16(cur.kb0, afB, zz, 0, 0, 0);
            f4_t sYA = __builtin_amdgcn_mfma_f32_16x16x32_bf16(cur.kb1, afA, zz, 0, 0, 0);
            f4_t sYB = __builtin_amdgcn_mfma_f32_16x16x32_bf16(cur.kb1, afB, zz, 0, 0, 0);

            KVTile nxt;
            if (jt < 15)
                nxt = load_tile(kb_base + (size_t)(jt + 1) * 1024,
                                v_base + (size_t)(jt + 1) * 1536, m, quad);

            bf8_t pXA = expack(sXA), pXB = expack(sXB);
            bf8_t pYA = expack(sYA), pYB = expack(sYB);
            bf8_t f0 = vpad(cur.v[0]), f1 = vpad(cur.v[1]), f2 = vpad(cur.v[2]);
            bf8_t g0 = vpad(cur.v[3]), g1 = vpad(cur.v[4]), g2 = vpad(cur.v[5]);

            acc[0] = __builtin_amdgcn_mfma_f32_16x16x32_bf16(pXA, f0, acc[0], 0, 0, 0);
            acc[0] = __builtin_amdgcn_mfma_f32_16x16x32_bf16(pYA, g0, acc[0], 0, 0, 0);
            acc[1] = __builtin_amdgcn_mfma_f32_16x16x32_bf16(pXA, f1, acc[1], 0, 0, 0);
            acc[1] = __builtin_amdgcn_mfma_f32_16x16x32_bf16(pYA, g1, acc[1], 0, 0, 0);
            acc[2] = __builtin_amdgcn_mfma_f32_16x16x32_bf16(pXA, f2, acc[2], 0, 0, 0);
            acc[2] = __builtin_amdgcn_mfma_f32_16x16x32_bf16(pYA, g2, acc[2], 0, 0, 0);
            acc[3] = __builtin_amdgcn_mfma_f32_16x16x32_bf16(pXB, f0, acc[3], 0, 0, 0);
            acc[3] = __builtin_amdgcn_mfma_f32_16x16x32_bf16(pYB, g0, acc[3], 0, 0, 0);
            acc[4] = __builtin_amdgcn_mfma_f32_16x16x32_bf16(pXB, f1, acc[4], 0, 0, 0);
            acc[4] = __builtin_amdgcn_mfma_f32_16x16x32_bf16(pYB, g1, acc[4], 0, 0, 0);
            acc[5] = __builtin_amdgcn_mfma_f32_16x16x32_bf16(pXB, f2, acc[5], 0, 0, 0);
            acc[5] = __builtin_amdgcn_mfma_f32_16x16x32_bf16(pYB, g2, acc[5], 0, 0, 0);

            cur = nxt;
        }

        #pragma unroll
        for (int r = 0; r < 4; ++r) {
            sh.red[w][quad * 4 + r][m]           = acc[0][r];
            sh.red[w][quad * 4 + r][16 + m]      = acc[1][r];
            sh.red[w][quad * 4 + r][32 + m]      = acc[2][r];
            sh.red[w][16 + quad * 4 + r][m]      = acc[3][r];
            sh.red[w][16 + quad * 4 + r][16 + m] = acc[4][r];
            sh.red[w][16 + quad * 4 + r][32 + m] = acc[5][r];
        }
        __syncthreads();

        #pragma unroll
        for (int u = 0; u < 6; ++u) {
            int e = t + u * 256;
            int rr = e / 48, cc = e % 48;
            sh.red[0][rr][cc] = sh.red[0][rr][cc] + sh.red[1][rr][cc]
                              + sh.red[2][rr][cc] + sh.red[3][rr][cc];
        }
        __syncthreads();

        if (t < 32) {
            const int i = i0 + t;
            float L   = sh.red[0][t][40];
            float inv = 1.0f / L;
            float o[40];
            #pragma unroll
            for (int z = 0; z < 40; ++z) o[z] = sh.red[0][t][z] * inv;

            ushort_t* f = featsb + (size_t)i * 576;
            #pragma unroll
            for (int c = 0; c < 16; ++c) f[h * 16 + c] = bfr(o[c]);

            float R[9], T[3];
            #pragma unroll
            for (int z = 0; z < 9; ++z) R[z] = rot[(size_t)i * 9 + z];
            #pragma unroll
            for (int d = 0; d < 3; ++d) T[d] = trans[(size_t)i * 3 + d];

            #pragma unroll
            for (int p8 = 0; p8 < 8; ++p8) {
                float g0 = o[16 + p8 * 3 + 0] - T[0];
                float g1 = o[16 + p8 * 3 + 1] - T[1];
                float g2 = o[16 + p8 * 3 + 2] - T[2];
                float xx = R[0] * g0 + R[3] * g1 + R[6] * g2;
                float yy = R[1] * g0 + R[4] * g1 + R[7] * g2;
                float zz = R[2] * g0 + R[5] * g1 + R[8] * g2;
                float dist = sqrtf(xx * xx + yy * yy + zz * zz + EPSm);
                f[192 + h * 8 + p8] = bfr(xx);
                f[288 + h * 8 + p8] = bfr(yy);
                f[384 + h * 8 + p8] = bfr(zz);
                f[480 + h * 8 + p8] = bfr(dist);
            }
        }
    }
    gridbar(bar + 3);

    // ===== phase 4: gemm2 out = featsb @ Woutb^T + bout  (192 tiles) =====
    if (bid < 192)
        gemm64(bid % 6, bid / 6, t, featsb, Woutb, bout, out, 384, 576, sh);
}

// ---------------------------------------------------------------------------
extern "C" void kernel_launch(void* const* d_in, const int* in_sizes, int n_in,
                              void* d_out, int out_size, void* d_ws, size_t ws_size,
                              hipStream_t stream)
{
    const float* s     = (const float*)d_in[0];
    const float* rot   = (const float*)d_in[1];
    const float* trans = (const float*)d_in[2];
    const float* mask  = (const float*)d_in[3];
    const float* Wq    = (const float*)d_in[4];
    const float* bq    = (const float*)d_in[5];
    const float* Wkv   = (const float*)d_in[6];
    const float* bkv   = (const float*)d_in[7];
    const float* Wqp   = (const float*)d_in[8];
    const float* bqp   = (const float*)d_in[9];
    const float* Wkvp  = (const float*)d_in[10];
    const float* bkvp  = (const float*)d_in[11];
    const float* hwv   = (const float*)d_in[12];
    const float* Wout  = (const float*)d_in[13];
    const float* bout  = (const float*)d_in[14];
    float* out = (float*)d_out;
    float* ws  = (float*)d_ws;

    if (ws_size < (size_t)WS_FLOATS * sizeof(float)) return;

    float*    Pall   = ws + OFF_PALL;
    ushort_t* Wallb  = (ushort_t*)(ws + OFF_WALLB);
    float*    ball   = ws + OFF_BALL;
    ushort_t* sb     = (ushort_t*)(ws + OFF_SB);
    ushort_t* Woutb  = (ushort_t*)(ws + OFF_WOUTB);
    ushort_t* featsb = (ushort_t*)(ws + OFF_FEATSB);
    ushort_t* AU     = (ushort_t*)(ws + OFF_AU);
    ushort_t* KU     = (ushort_t*)(ws + OFF_KU);
    ushort_t* VU     = (ushort_t*)(ws + OFF_VU);
    unsigned* bar    = (unsigned*)(ws + OFF_BAR);

    // zero the 4 barrier counters (captured async op; re-runs every replay)
    hipMemsetAsync(bar, 0, 4 * sizeof(unsigned), stream);

    mega<<<dim3(NBLK), 256, 0, stream>>>(
        s, rot, trans, mask, Wq, bq, Wkv, bkv, Wqp, bqp, Wkvp, bkvp,
        hwv, Wout, bout,
        Pall, Wallb, ball, sb, Woutb, featsb, AU, KU, VU, bar, out);
}